// Round 5
// baseline (1824.050 us; speedup 1.0000x reference)
//
#include <hip/hip_runtime.h>
#include <hip/hip_bf16.h>

// Problem constants
#define BB 64
#define TT 2048
#define II 128
#define HH 256
#define OO 128

typedef float f32x2 __attribute__((ext_vector_type(2)));
typedef float f32x4v __attribute__((ext_vector_type(4)));
typedef short bf16x8 __attribute__((ext_vector_type(8)));

// ---------------------------------------------------------------------------
// Tiled fp32 GEMM: C[M,N] = A[M,K] * B[N,K]^T + bias[N]   (unchanged)
// ---------------------------------------------------------------------------
#define BM 64
#define BN 64
#define BKT 32

__global__ __launch_bounds__(256) void gemm_f32_bt(
    const float* __restrict__ A, const float* __restrict__ B,
    const float* __restrict__ bias, float* __restrict__ C,
    int M, int N, int K)
{
    __shared__ __align__(16) float As[BKT][BM + 4];
    __shared__ __align__(16) float Bs[BKT][BN + 4];

    const int t  = threadIdx.x;
    const int m0 = blockIdx.x * BM;
    const int n0 = blockIdx.y * BN;
    const int r  = t >> 3;         // 0..31
    const int kq = (t & 7) * 4;    // 0,4,...,28
    const int tx = t & 15;
    const int ty = t >> 4;

    float acc[4][4] = {};

    for (int k0 = 0; k0 < K; k0 += BKT) {
        float4 a0 = *(const float4*)&A[(size_t)(m0 + r)      * K + k0 + kq];
        float4 a1 = *(const float4*)&A[(size_t)(m0 + r + 32) * K + k0 + kq];
        float4 b0 = *(const float4*)&B[(size_t)(n0 + r)      * K + k0 + kq];
        float4 b1 = *(const float4*)&B[(size_t)(n0 + r + 32) * K + k0 + kq];

        __syncthreads();
        As[kq + 0][r] = a0.x; As[kq + 1][r] = a0.y; As[kq + 2][r] = a0.z; As[kq + 3][r] = a0.w;
        As[kq + 0][r + 32] = a1.x; As[kq + 1][r + 32] = a1.y; As[kq + 2][r + 32] = a1.z; As[kq + 3][r + 32] = a1.w;
        Bs[kq + 0][r] = b0.x; Bs[kq + 1][r] = b0.y; Bs[kq + 2][r] = b0.z; Bs[kq + 3][r] = b0.w;
        Bs[kq + 0][r + 32] = b1.x; Bs[kq + 1][r + 32] = b1.y; Bs[kq + 2][r + 32] = b1.z; Bs[kq + 3][r + 32] = b1.w;
        __syncthreads();

#pragma unroll
        for (int k = 0; k < BKT; ++k) {
            float4 avv = *(const float4*)&As[k][ty * 4];
            float4 bvv = *(const float4*)&Bs[k][tx * 4];
            const float* av = &avv.x;
            const float* bv = &bvv.x;
#pragma unroll
            for (int i = 0; i < 4; ++i)
#pragma unroll
                for (int j = 0; j < 4; ++j)
                    acc[i][j] = fmaf(av[i], bv[j], acc[i][j]);
        }
    }

#pragma unroll
    for (int i = 0; i < 4; ++i) {
        float4 o;
        o.x = acc[i][0] + bias[n0 + tx * 4 + 0];
        o.y = acc[i][1] + bias[n0 + tx * 4 + 1];
        o.z = acc[i][2] + bias[n0 + tx * 4 + 2];
        o.w = acc[i][3] + bias[n0 + tx * 4 + 3];
        *(float4*)&C[(size_t)(m0 + ty * 4 + i) * N + n0 + tx * 4] = o;
    }
}

// Same GEMM but A is bf16 (hs), output fp32.  (unchanged)
typedef unsigned short ushortv4 __attribute__((ext_vector_type(4)));

__device__ __forceinline__ float bf16bits_to_f32(unsigned short u) {
    return __uint_as_float((unsigned)u << 16);
}

__global__ __launch_bounds__(256) void gemm_bf16a_bt(
    const unsigned short* __restrict__ A, const float* __restrict__ B,
    const float* __restrict__ bias, float* __restrict__ C,
    int M, int N, int K)
{
    __shared__ __align__(16) float As[BKT][BM + 4];
    __shared__ __align__(16) float Bs[BKT][BN + 4];

    const int t  = threadIdx.x;
    const int m0 = blockIdx.x * BM;
    const int n0 = blockIdx.y * BN;
    const int r  = t >> 3;
    const int kq = (t & 7) * 4;
    const int tx = t & 15;
    const int ty = t >> 4;

    float acc[4][4] = {};

    for (int k0 = 0; k0 < K; k0 += BKT) {
        ushortv4 a0 = *(const ushortv4*)&A[(size_t)(m0 + r)      * K + k0 + kq];
        ushortv4 a1 = *(const ushortv4*)&A[(size_t)(m0 + r + 32) * K + k0 + kq];
        float4  b0 = *(const float4*)&B[(size_t)(n0 + r)      * K + k0 + kq];
        float4  b1 = *(const float4*)&B[(size_t)(n0 + r + 32) * K + k0 + kq];

        __syncthreads();
        As[kq + 0][r] = bf16bits_to_f32(a0[0]); As[kq + 1][r] = bf16bits_to_f32(a0[1]);
        As[kq + 2][r] = bf16bits_to_f32(a0[2]); As[kq + 3][r] = bf16bits_to_f32(a0[3]);
        As[kq + 0][r + 32] = bf16bits_to_f32(a1[0]); As[kq + 1][r + 32] = bf16bits_to_f32(a1[1]);
        As[kq + 2][r + 32] = bf16bits_to_f32(a1[2]); As[kq + 3][r + 32] = bf16bits_to_f32(a1[3]);
        Bs[kq + 0][r] = b0.x; Bs[kq + 1][r] = b0.y; Bs[kq + 2][r] = b0.z; Bs[kq + 3][r] = b0.w;
        Bs[kq + 0][r + 32] = b1.x; Bs[kq + 1][r + 32] = b1.y; Bs[kq + 2][r + 32] = b1.z; Bs[kq + 3][r + 32] = b1.w;
        __syncthreads();

#pragma unroll
        for (int k = 0; k < BKT; ++k) {
            float4 avv = *(const float4*)&As[k][ty * 4];
            float4 bvv = *(const float4*)&Bs[k][tx * 4];
            const float* av = &avv.x;
            const float* bv = &bvv.x;
#pragma unroll
            for (int i = 0; i < 4; ++i)
#pragma unroll
                for (int j = 0; j < 4; ++j)
                    acc[i][j] = fmaf(av[i], bv[j], acc[i][j]);
        }
    }

#pragma unroll
    for (int i = 0; i < 4; ++i) {
        float4 o;
        o.x = acc[i][0] + bias[n0 + tx * 4 + 0];
        o.y = acc[i][1] + bias[n0 + tx * 4 + 1];
        o.z = acc[i][2] + bias[n0 + tx * 4 + 2];
        o.w = acc[i][3] + bias[n0 + tx * 4 + 3];
        *(float4*)&C[(size_t)(m0 + ty * 4 + i) * N + n0 + tx * 4] = o;
    }
}

// ---------------------------------------------------------------------------
// Recurrence v5 — MFMA. R1-R4 lesson: the allocator refuses big reloadable
// VGPR arrays (R4: weights -> AGPR + accvgpr_read/write shuttle = the 1600us).
// MFMA reads its operands from AGPRs NATIVELY (gfx950 unified file), so hold
// Wh as bf16 B-fragments and let the allocator put them wherever it likes.
//
// 4 blocks x 512 threads (8 waves, waves_per_eu(2,2)). Block owns 16 batches;
// wave owns a 32-unit N-slice (2 N-tiles of 16). Per step:
//   H_new[16,256] = tanh( H[16,256] @ Wh^T (MFMA, bf16 in / f32 acc)
//                         + xproj_t + bh )
// Frag layouts (m89-verified family):
//   A[i][k]: i = lane&15, k = (lane>>4)*8 + b   (8 bf16 = 1 ds_read_b128)
//   B[k][j]: j = lane&15, k = (lane>>4)*8 + b   (Wh row-contiguous load)
//   D[i][j]: j = lane&15, i = (lane>>4)*4 + r
// h state bf16 (RNE) in LDS, double-buffered; accumulate/tanh/xproj fp32.
// ---------------------------------------------------------------------------
#define G 16        // batches per block
#define HPAD 264    // bf16 elems per h row: 528B rows -> conflict-free b128
#define XPPAD 260   // f32 elems per xp row: bank-shifts the m-groups

__device__ __forceinline__ unsigned short f2bf(float f) {
    union { __hip_bfloat16 h; unsigned short u; } cv;
    cv.h = __float2bfloat16(f);   // RNE
    return cv.u;
}

__device__ __forceinline__ float tanh_fast(float x) {
    float e = __expf(2.0f * x);
    return 1.0f - 2.0f * __builtin_amdgcn_rcpf(e + 1.0f);
}

__global__ __launch_bounds__(512) __attribute__((amdgpu_waves_per_eu(2, 2)))
void rnn_recurrence_mfma(
    const float* __restrict__ xproj, const float* __restrict__ Wh,
    const float* __restrict__ bh, unsigned short* __restrict__ hs)
{
    __shared__ __align__(16) unsigned short hbl[2][G][HPAD];
    __shared__ __align__(16) float xpl[2][G][XPPAD];

    const int blk  = blockIdx.x;         // 0..3
    const int tid  = threadIdx.x;        // 0..511
    const int wave = tid >> 6;           // 0..7
    const int lane = tid & 63;
    const int l15  = lane & 15;
    const int lg   = lane >> 4;          // 0..3
    const int n0   = wave * 32;          // this wave's unit base

    // ---- one-time: load B-fragments of Wh (bf16), 16 frags x 4 regs ----
#define LOADB(nt, kt, dst) { \
        const float* wp = Wh + (size_t)(n0 + (nt)*16 + l15) * HH + (kt)*32 + lg*8; \
        float4 w0 = *(const float4*)wp; float4 w1 = *(const float4*)(wp + 4); \
        dst[0] = (short)f2bf(w0.x); dst[1] = (short)f2bf(w0.y); \
        dst[2] = (short)f2bf(w0.z); dst[3] = (short)f2bf(w0.w); \
        dst[4] = (short)f2bf(w1.x); dst[5] = (short)f2bf(w1.y); \
        dst[6] = (short)f2bf(w1.z); dst[7] = (short)f2bf(w1.w); }

    bf16x8 B00, B01, B02, B03, B04, B05, B06, B07;
    bf16x8 B10, B11, B12, B13, B14, B15, B16, B17;
    LOADB(0, 0, B00) LOADB(0, 1, B01) LOADB(0, 2, B02) LOADB(0, 3, B03)
    LOADB(0, 4, B04) LOADB(0, 5, B05) LOADB(0, 6, B06) LOADB(0, 7, B07)
    LOADB(1, 0, B10) LOADB(1, 1, B11) LOADB(1, 2, B12) LOADB(1, 3, B13)
    LOADB(1, 4, B14) LOADB(1, 5, B15) LOADB(1, 6, B16) LOADB(1, 7, B17)

    const float bh0 = bh[n0 + l15];
    const float bh1 = bh[n0 + 16 + l15];

    // ---- prologue: h0 = 0; stage xproj[t=0] ----
    for (int i = tid; i < G * HPAD; i += 512)
        ((unsigned short*)&hbl[0][0][0])[i] = 0;
    {
        const int g = tid >> 5, q = tid & 31;
        const float* xsrc = xproj + ((size_t)(blk * G + g) * TT + 0) * HH + q * 8;
        *(float4*)&xpl[0][g][q * 8]     = *(const float4*)xsrc;
        *(float4*)&xpl[0][g][q * 8 + 4] = *(const float4*)(xsrc + 4);
    }
    __syncthreads();

    for (int t = 0; t < TT; ++t) {
        const int p = t & 1;

        // 1. prefetch xproj[t+1] into regs (hidden under MFMAs)
        const int g = tid >> 5, q = tid & 31;
        const int tn = (t + 1 < TT) ? (t + 1) : (TT - 1);
        const float* xsrc = xproj + ((size_t)(blk * G + g) * TT + tn) * HH + q * 8;
        float4 xpre0 = *(const float4*)xsrc;
        float4 xpre1 = *(const float4*)(xsrc + 4);

        // 2. A-fragments of current h from LDS (8 x ds_read_b128)
        const unsigned short* hrow = &hbl[p][l15][lg * 8];
        bf16x8 a0 = *(const bf16x8*)(hrow + 0 * 32);
        bf16x8 a1 = *(const bf16x8*)(hrow + 1 * 32);
        bf16x8 a2 = *(const bf16x8*)(hrow + 2 * 32);
        bf16x8 a3 = *(const bf16x8*)(hrow + 3 * 32);
        bf16x8 a4 = *(const bf16x8*)(hrow + 4 * 32);
        bf16x8 a5 = *(const bf16x8*)(hrow + 5 * 32);
        bf16x8 a6 = *(const bf16x8*)(hrow + 6 * 32);
        bf16x8 a7 = *(const bf16x8*)(hrow + 7 * 32);

        // 3. MFMA: 4 chains of 4 (2 N-tiles x 2 K-halves)
        f32x4v c00 = {0.f, 0.f, 0.f, 0.f}, c01 = {0.f, 0.f, 0.f, 0.f};
        f32x4v c10 = {0.f, 0.f, 0.f, 0.f}, c11 = {0.f, 0.f, 0.f, 0.f};
        c00 = __builtin_amdgcn_mfma_f32_16x16x32_bf16(a0, B00, c00, 0, 0, 0);
        c10 = __builtin_amdgcn_mfma_f32_16x16x32_bf16(a0, B10, c10, 0, 0, 0);
        c01 = __builtin_amdgcn_mfma_f32_16x16x32_bf16(a4, B04, c01, 0, 0, 0);
        c11 = __builtin_amdgcn_mfma_f32_16x16x32_bf16(a4, B14, c11, 0, 0, 0);
        c00 = __builtin_amdgcn_mfma_f32_16x16x32_bf16(a1, B01, c00, 0, 0, 0);
        c10 = __builtin_amdgcn_mfma_f32_16x16x32_bf16(a1, B11, c10, 0, 0, 0);
        c01 = __builtin_amdgcn_mfma_f32_16x16x32_bf16(a5, B05, c01, 0, 0, 0);
        c11 = __builtin_amdgcn_mfma_f32_16x16x32_bf16(a5, B15, c11, 0, 0, 0);
        c00 = __builtin_amdgcn_mfma_f32_16x16x32_bf16(a2, B02, c00, 0, 0, 0);
        c10 = __builtin_amdgcn_mfma_f32_16x16x32_bf16(a2, B12, c10, 0, 0, 0);
        c01 = __builtin_amdgcn_mfma_f32_16x16x32_bf16(a6, B06, c01, 0, 0, 0);
        c11 = __builtin_amdgcn_mfma_f32_16x16x32_bf16(a6, B16, c11, 0, 0, 0);
        c00 = __builtin_amdgcn_mfma_f32_16x16x32_bf16(a3, B03, c00, 0, 0, 0);
        c10 = __builtin_amdgcn_mfma_f32_16x16x32_bf16(a3, B13, c10, 0, 0, 0);
        c01 = __builtin_amdgcn_mfma_f32_16x16x32_bf16(a7, B07, c01, 0, 0, 0);
        c11 = __builtin_amdgcn_mfma_f32_16x16x32_bf16(a7, B17, c11, 0, 0, 0);

        // 4. epilogue: add xproj + bias, tanh, write h (LDS bf16) and hs
#pragma unroll
        for (int r = 0; r < 4; ++r) {
            const int m = lg * 4 + r;
            float pre0 = c00[r] + c01[r] + xpl[p][m][n0 + l15] + bh0;
            float pre1 = c10[r] + c11[r] + xpl[p][m][n0 + 16 + l15] + bh1;
            unsigned short u0 = f2bf(tanh_fast(pre0));
            unsigned short u1 = f2bf(tanh_fast(pre1));
            hbl[p ^ 1][m][n0 + l15]      = u0;
            hbl[p ^ 1][m][n0 + 16 + l15] = u1;
            unsigned short* hd = hs + ((size_t)(blk * G + m) * TT + t) * HH;
            hd[n0 + l15]      = u0;
            hd[n0 + 16 + l15] = u1;
        }

        // 5. land the xproj prefetch into the other buffer
        *(float4*)&xpl[p ^ 1][g][q * 8]     = xpre0;
        *(float4*)&xpl[p ^ 1][g][q * 8 + 4] = xpre1;

        __syncthreads();
    }
}

// ---------------------------------------------------------------------------
extern "C" void kernel_launch(void* const* d_in, const int* in_sizes, int n_in,
                              void* d_out, int out_size, void* d_ws, size_t ws_size,
                              hipStream_t stream)
{
    const float* x  = (const float*)d_in[0];   // [B,T,I]
    const float* Wi = (const float*)d_in[1];   // [H,I]
    const float* bi = (const float*)d_in[2];   // [H]
    const float* Wh = (const float*)d_in[3];   // [H,H]
    const float* bh = (const float*)d_in[4];   // [H]
    const float* Wo = (const float*)d_in[5];   // [O,H]
    const float* bo = (const float*)d_in[6];   // [O]
    float* out = (float*)d_out;                // [B,T,O] fp32

    const int M = BB * TT;                     // 131072 flattened rows

    // workspace layout: xproj fp32 [M,H] (134MB) | hs bf16 [M,H] (67MB)
    float* xproj = (float*)d_ws;
    unsigned short* hs = (unsigned short*)((char*)d_ws + (size_t)M * HH * sizeof(float));

    // Phase 1: xproj = x * Wi^T + bi
    gemm_f32_bt<<<dim3(M / BM, HH / BN), 256, 0, stream>>>(x, Wi, bi, xproj, M, HH, II);

    // Phase 2: sequential recurrence over T, batch-tiled via MFMA
    rnn_recurrence_mfma<<<dim3(4), 512, 0, stream>>>(xproj, Wh, bh, hs);

    // Phase 3: out = hs * Wo^T + bo
    gemm_bf16a_bt<<<dim3(M / BM, OO / BN), 256, 0, stream>>>(
        hs, Wo, bo, out, M, OO, HH);
}

// Round 6
// 1519.525 us; speedup vs baseline: 1.2004x; 1.2004x over previous
//
#include <hip/hip_runtime.h>
#include <hip/hip_bf16.h>

// Problem constants
#define BB 64
#define TT 2048
#define II 128
#define HH 256
#define OO 128

typedef float f32x4v __attribute__((ext_vector_type(4)));
typedef short bf16x8 __attribute__((ext_vector_type(8)));

// ---------------------------------------------------------------------------
// Tiled fp32 GEMM: C[M,N] = A[M,K] * B[N,K]^T + bias[N]   (unchanged)
// ---------------------------------------------------------------------------
#define BM 64
#define BN 64
#define BKT 32

__global__ __launch_bounds__(256) void gemm_f32_bt(
    const float* __restrict__ A, const float* __restrict__ B,
    const float* __restrict__ bias, float* __restrict__ C,
    int M, int N, int K)
{
    __shared__ __align__(16) float As[BKT][BM + 4];
    __shared__ __align__(16) float Bs[BKT][BN + 4];

    const int t  = threadIdx.x;
    const int m0 = blockIdx.x * BM;
    const int n0 = blockIdx.y * BN;
    const int r  = t >> 3;         // 0..31
    const int kq = (t & 7) * 4;    // 0,4,...,28
    const int tx = t & 15;
    const int ty = t >> 4;

    float acc[4][4] = {};

    for (int k0 = 0; k0 < K; k0 += BKT) {
        float4 a0 = *(const float4*)&A[(size_t)(m0 + r)      * K + k0 + kq];
        float4 a1 = *(const float4*)&A[(size_t)(m0 + r + 32) * K + k0 + kq];
        float4 b0 = *(const float4*)&B[(size_t)(n0 + r)      * K + k0 + kq];
        float4 b1 = *(const float4*)&B[(size_t)(n0 + r + 32) * K + k0 + kq];

        __syncthreads();
        As[kq + 0][r] = a0.x; As[kq + 1][r] = a0.y; As[kq + 2][r] = a0.z; As[kq + 3][r] = a0.w;
        As[kq + 0][r + 32] = a1.x; As[kq + 1][r + 32] = a1.y; As[kq + 2][r + 32] = a1.z; As[kq + 3][r + 32] = a1.w;
        Bs[kq + 0][r] = b0.x; Bs[kq + 1][r] = b0.y; Bs[kq + 2][r] = b0.z; Bs[kq + 3][r] = b0.w;
        Bs[kq + 0][r + 32] = b1.x; Bs[kq + 1][r + 32] = b1.y; Bs[kq + 2][r + 32] = b1.z; Bs[kq + 3][r + 32] = b1.w;
        __syncthreads();

#pragma unroll
        for (int k = 0; k < BKT; ++k) {
            float4 avv = *(const float4*)&As[k][ty * 4];
            float4 bvv = *(const float4*)&Bs[k][tx * 4];
            const float* av = &avv.x;
            const float* bv = &bvv.x;
#pragma unroll
            for (int i = 0; i < 4; ++i)
#pragma unroll
                for (int j = 0; j < 4; ++j)
                    acc[i][j] = fmaf(av[i], bv[j], acc[i][j]);
        }
    }

#pragma unroll
    for (int i = 0; i < 4; ++i) {
        float4 o;
        o.x = acc[i][0] + bias[n0 + tx * 4 + 0];
        o.y = acc[i][1] + bias[n0 + tx * 4 + 1];
        o.z = acc[i][2] + bias[n0 + tx * 4 + 2];
        o.w = acc[i][3] + bias[n0 + tx * 4 + 3];
        *(float4*)&C[(size_t)(m0 + ty * 4 + i) * N + n0 + tx * 4] = o;
    }
}

// Same GEMM but A is bf16 (hs) with WITHIN-32 PERMUTED columns:
// stored pos d (within each 32-block) holds true unit ((d>>1) + 16*(d&1)).
// The As staging un-permutes (it was already 4 scalar LDS writes — free).
typedef unsigned short ushortv4 __attribute__((ext_vector_type(4)));

__device__ __forceinline__ float bf16bits_to_f32(unsigned short u) {
    return __uint_as_float((unsigned)u << 16);
}

__global__ __launch_bounds__(256) void gemm_bf16a_bt(
    const unsigned short* __restrict__ A, const float* __restrict__ B,
    const float* __restrict__ bias, float* __restrict__ C,
    int M, int N, int K)
{
    __shared__ __align__(16) float As[BKT][BM + 4];
    __shared__ __align__(16) float Bs[BKT][BN + 4];

    const int t  = threadIdx.x;
    const int m0 = blockIdx.x * BM;
    const int n0 = blockIdx.y * BN;
    const int r  = t >> 3;
    const int kq = (t & 7) * 4;
    const int kh = kq >> 1;        // un-permute: rows {kh, kh+16, kh+1, kh+17}
    const int tx = t & 15;
    const int ty = t >> 4;

    float acc[4][4] = {};

    for (int k0 = 0; k0 < K; k0 += BKT) {
        ushortv4 a0 = *(const ushortv4*)&A[(size_t)(m0 + r)      * K + k0 + kq];
        ushortv4 a1 = *(const ushortv4*)&A[(size_t)(m0 + r + 32) * K + k0 + kq];
        float4  b0 = *(const float4*)&B[(size_t)(n0 + r)      * K + k0 + kq];
        float4  b1 = *(const float4*)&B[(size_t)(n0 + r + 32) * K + k0 + kq];

        __syncthreads();
        As[kh + 0][r]  = bf16bits_to_f32(a0[0]); As[kh + 16][r] = bf16bits_to_f32(a0[1]);
        As[kh + 1][r]  = bf16bits_to_f32(a0[2]); As[kh + 17][r] = bf16bits_to_f32(a0[3]);
        As[kh + 0][r + 32]  = bf16bits_to_f32(a1[0]); As[kh + 16][r + 32] = bf16bits_to_f32(a1[1]);
        As[kh + 1][r + 32]  = bf16bits_to_f32(a1[2]); As[kh + 17][r + 32] = bf16bits_to_f32(a1[3]);
        Bs[kq + 0][r] = b0.x; Bs[kq + 1][r] = b0.y; Bs[kq + 2][r] = b0.z; Bs[kq + 3][r] = b0.w;
        Bs[kq + 0][r + 32] = b1.x; Bs[kq + 1][r + 32] = b1.y; Bs[kq + 2][r + 32] = b1.z; Bs[kq + 3][r + 32] = b1.w;
        __syncthreads();

#pragma unroll
        for (int k = 0; k < BKT; ++k) {
            float4 avv = *(const float4*)&As[k][ty * 4];
            float4 bvv = *(const float4*)&Bs[k][tx * 4];
            const float* av = &avv.x;
            const float* bv = &bvv.x;
#pragma unroll
            for (int i = 0; i < 4; ++i)
#pragma unroll
                for (int j = 0; j < 4; ++j)
                    acc[i][j] = fmaf(av[i], bv[j], acc[i][j]);
        }
    }

#pragma unroll
    for (int i = 0; i < 4; ++i) {
        float4 o;
        o.x = acc[i][0] + bias[n0 + tx * 4 + 0];
        o.y = acc[i][1] + bias[n0 + tx * 4 + 1];
        o.z = acc[i][2] + bias[n0 + tx * 4 + 2];
        o.w = acc[i][3] + bias[n0 + tx * 4 + 3];
        *(float4*)&C[(size_t)(m0 + ty * 4 + i) * N + n0 + tx * 4] = o;
    }
}

// ---------------------------------------------------------------------------
// Recurrence v6 (MFMA core kept from v5; everything around it rebuilt):
//  - hs global stores DEFERRED one step -> barrier's vmcnt(0) drain is free
//  - xproj read per-lane direct from global (L3), prefetched 1 step ahead,
//    FOLDED with bh into MFMA C-in -> epilogue = add + tanh + cvt_pk only
//  - h LDS layout permuted (wave's 2 N-tiles interleaved: unit n0+16t+j at
//    pos n0+2j+t) -> one ds_write_b32 + one global_store_dword per pair,
//    2-way bank pattern (free). K-permutation absorbed by one-time B-frag
//    gather and phase-3 As staging.
//  - v_cvt_pk_bf16_f32: 2 outputs per instruction
// ---------------------------------------------------------------------------
#define G 16        // batches per block
#define HPAD 264    // ushorts per h row: 528B = 33*16B -> uniform bank spread

__device__ __forceinline__ unsigned short f2bf(float f) {
    union { __hip_bfloat16 h; unsigned short u; } cv;
    cv.h = __float2bfloat16(f);   // RNE (one-time weight conversion only)
    return cv.u;
}

__device__ __forceinline__ float tanh_fast(float x) {
    float e = __expf(2.0f * x);
    return 1.0f - 2.0f * __builtin_amdgcn_rcpf(e + 1.0f);
}

__global__ __launch_bounds__(512) __attribute__((amdgpu_waves_per_eu(2, 2)))
void rnn_recurrence_mfma(
    const float* __restrict__ xproj, const float* __restrict__ Wh,
    const float* __restrict__ bh, unsigned short* __restrict__ hs)
{
    __shared__ __align__(16) unsigned short hbl[2][G][HPAD];

    const int blk  = blockIdx.x;         // 0..3
    const int tid  = threadIdx.x;        // 0..511
    const int wave = tid >> 6;           // 0..7
    const int lane = tid & 63;
    const int l15  = lane & 15;
    const int lg   = lane >> 4;          // 0..3
    const int n0   = wave * 32;          // this wave's unit base

    // ---- one-time B-frags, K-dim gathered through the storage permutation:
    // frag element b <-> k-slot lg*8+b <-> Wh column kt*32 + lg*4 + (b>>1) + 16*(b&1)
#define LOADB(nt, kt, dst) { \
        const float* wp = Wh + (size_t)(n0 + (nt)*16 + l15) * HH + (kt)*32 + lg*4; \
        dst[0] = (short)f2bf(wp[0]);  dst[1] = (short)f2bf(wp[16]); \
        dst[2] = (short)f2bf(wp[1]);  dst[3] = (short)f2bf(wp[17]); \
        dst[4] = (short)f2bf(wp[2]);  dst[5] = (short)f2bf(wp[18]); \
        dst[6] = (short)f2bf(wp[3]);  dst[7] = (short)f2bf(wp[19]); }

    bf16x8 B00, B01, B02, B03, B04, B05, B06, B07;
    bf16x8 B10, B11, B12, B13, B14, B15, B16, B17;
    LOADB(0, 0, B00) LOADB(0, 1, B01) LOADB(0, 2, B02) LOADB(0, 3, B03)
    LOADB(0, 4, B04) LOADB(0, 5, B05) LOADB(0, 6, B06) LOADB(0, 7, B07)
    LOADB(1, 0, B10) LOADB(1, 1, B11) LOADB(1, 2, B12) LOADB(1, 3, B13)
    LOADB(1, 4, B14) LOADB(1, 5, B15) LOADB(1, 6, B16) LOADB(1, 7, B17)

    const float bh0 = bh[n0 + l15];
    const float bh1 = bh[n0 + 16 + l15];

    // per-thread row pointers: 4 batch rows (m = lg*4 + r)
    const int mb = blk * G + lg * 4;
    const float* xq0 = xproj + (size_t)(mb + 0) * TT * HH + n0 + l15;
    const float* xq1 = xproj + (size_t)(mb + 1) * TT * HH + n0 + l15;
    const float* xq2 = xproj + (size_t)(mb + 2) * TT * HH + n0 + l15;
    const float* xq3 = xproj + (size_t)(mb + 3) * TT * HH + n0 + l15;
    unsigned short* hq0 = hs + (size_t)(mb + 0) * TT * HH + n0 + 2 * l15;
    unsigned short* hq1 = hs + (size_t)(mb + 1) * TT * HH + n0 + 2 * l15;
    unsigned short* hq2 = hs + (size_t)(mb + 2) * TT * HH + n0 + 2 * l15;
    unsigned short* hq3 = hs + (size_t)(mb + 3) * TT * HH + n0 + 2 * l15;

    // prologue: zero h buffer 0; load x for t=0
    for (int i = tid; i < G * HPAD; i += 512)
        ((unsigned short*)hbl[0])[i] = 0;
    float xv0 = xq0[0],  xv1 = xq1[0],  xv2 = xq2[0],  xv3 = xq3[0];
    float xv4 = xq0[16], xv5 = xq1[16], xv6 = xq2[16], xv7 = xq3[16];
    __syncthreads();

    unsigned int pk0 = 0, pk1 = 0, pk2 = 0, pk3 = 0;

    for (int t = 0; t < TT; ++t) {
        const int p = t & 1;

        // A-fragments of current h (8 x ds_read_b128, uniform bank spread)
        const unsigned short* hrow = &hbl[p][l15][lg * 8];
        bf16x8 a0 = *(const bf16x8*)(hrow + 0 * 32);
        bf16x8 a1 = *(const bf16x8*)(hrow + 1 * 32);
        bf16x8 a2 = *(const bf16x8*)(hrow + 2 * 32);
        bf16x8 a3 = *(const bf16x8*)(hrow + 3 * 32);
        bf16x8 a4 = *(const bf16x8*)(hrow + 4 * 32);
        bf16x8 a5 = *(const bf16x8*)(hrow + 5 * 32);
        bf16x8 a6 = *(const bf16x8*)(hrow + 6 * 32);
        bf16x8 a7 = *(const bf16x8*)(hrow + 7 * 32);

        // deferred hs stores for step t-1 (drain overlaps this whole step)
        if (t) {
            *(unsigned int*)hq0 = pk0; hq0 += HH;
            *(unsigned int*)hq1 = pk1; hq1 += HH;
            *(unsigned int*)hq2 = pk2; hq2 += HH;
            *(unsigned int*)hq3 = pk3; hq3 += HH;
        }

        // MFMA: bias and xproj folded into C-in; 4 chains of 4
        f32x4v c00 = {bh0, bh0, bh0, bh0};
        f32x4v c10 = {bh1, bh1, bh1, bh1};
        f32x4v c01 = {xv0, xv1, xv2, xv3};
        f32x4v c11 = {xv4, xv5, xv6, xv7};
        c00 = __builtin_amdgcn_mfma_f32_16x16x32_bf16(a0, B00, c00, 0, 0, 0);
        c10 = __builtin_amdgcn_mfma_f32_16x16x32_bf16(a0, B10, c10, 0, 0, 0);
        c01 = __builtin_amdgcn_mfma_f32_16x16x32_bf16(a4, B04, c01, 0, 0, 0);
        c11 = __builtin_amdgcn_mfma_f32_16x16x32_bf16(a4, B14, c11, 0, 0, 0);
        c00 = __builtin_amdgcn_mfma_f32_16x16x32_bf16(a1, B01, c00, 0, 0, 0);
        c10 = __builtin_amdgcn_mfma_f32_16x16x32_bf16(a1, B11, c10, 0, 0, 0);
        c01 = __builtin_amdgcn_mfma_f32_16x16x32_bf16(a5, B05, c01, 0, 0, 0);
        c11 = __builtin_amdgcn_mfma_f32_16x16x32_bf16(a5, B15, c11, 0, 0, 0);
        c00 = __builtin_amdgcn_mfma_f32_16x16x32_bf16(a2, B02, c00, 0, 0, 0);
        c10 = __builtin_amdgcn_mfma_f32_16x16x32_bf16(a2, B12, c10, 0, 0, 0);
        c01 = __builtin_amdgcn_mfma_f32_16x16x32_bf16(a6, B06, c01, 0, 0, 0);
        c11 = __builtin_amdgcn_mfma_f32_16x16x32_bf16(a6, B16, c11, 0, 0, 0);
        c00 = __builtin_amdgcn_mfma_f32_16x16x32_bf16(a3, B03, c00, 0, 0, 0);
        c10 = __builtin_amdgcn_mfma_f32_16x16x32_bf16(a3, B13, c10, 0, 0, 0);
        c01 = __builtin_amdgcn_mfma_f32_16x16x32_bf16(a7, B07, c01, 0, 0, 0);
        c11 = __builtin_amdgcn_mfma_f32_16x16x32_bf16(a7, B17, c11, 0, 0, 0);

        // epilogue: add halves, tanh, pack 2 bf16, one b32 LDS write per r
        const int q = (tid >> 5), dummy = q; (void)dummy;
        unsigned int* wr = (unsigned int*)&hbl[p ^ 1][lg * 4][n0 + 2 * l15];
        {
            float h0 = tanh_fast(c00[0] + c01[0]);
            float h1 = tanh_fast(c10[0] + c11[0]);
            asm("v_cvt_pk_bf16_f32 %0, %1, %2" : "=v"(pk0) : "v"(h0), "v"(h1));
            *(unsigned int*)&hbl[p ^ 1][lg * 4 + 0][n0 + 2 * l15] = pk0;
        }
        {
            float h0 = tanh_fast(c00[1] + c01[1]);
            float h1 = tanh_fast(c10[1] + c11[1]);
            asm("v_cvt_pk_bf16_f32 %0, %1, %2" : "=v"(pk1) : "v"(h0), "v"(h1));
            *(unsigned int*)&hbl[p ^ 1][lg * 4 + 1][n0 + 2 * l15] = pk1;
        }
        {
            float h0 = tanh_fast(c00[2] + c01[2]);
            float h1 = tanh_fast(c10[2] + c11[2]);
            asm("v_cvt_pk_bf16_f32 %0, %1, %2" : "=v"(pk2) : "v"(h0), "v"(h1));
            *(unsigned int*)&hbl[p ^ 1][lg * 4 + 2][n0 + 2 * l15] = pk2;
        }
        {
            float h0 = tanh_fast(c00[3] + c01[3]);
            float h1 = tanh_fast(c10[3] + c11[3]);
            asm("v_cvt_pk_bf16_f32 %0, %1, %2" : "=v"(pk3) : "v"(h0), "v"(h1));
            *(unsigned int*)&hbl[p ^ 1][lg * 4 + 3][n0 + 2 * l15] = pk3;
        }
        (void)wr;

        // prefetch x for t+1 (consumed as next step's MFMA C-in)
        xq0 += HH; xq1 += HH; xq2 += HH; xq3 += HH;
        xv0 = xq0[0];  xv1 = xq1[0];  xv2 = xq2[0];  xv3 = xq3[0];
        xv4 = xq0[16]; xv5 = xq1[16]; xv6 = xq2[16]; xv7 = xq3[16];

        __syncthreads();
    }

    // final stores (t = TT-1)
    *(unsigned int*)hq0 = pk0;
    *(unsigned int*)hq1 = pk1;
    *(unsigned int*)hq2 = pk2;
    *(unsigned int*)hq3 = pk3;
}

// ---------------------------------------------------------------------------
extern "C" void kernel_launch(void* const* d_in, const int* in_sizes, int n_in,
                              void* d_out, int out_size, void* d_ws, size_t ws_size,
                              hipStream_t stream)
{
    const float* x  = (const float*)d_in[0];   // [B,T,I]
    const float* Wi = (const float*)d_in[1];   // [H,I]
    const float* bi = (const float*)d_in[2];   // [H]
    const float* Wh = (const float*)d_in[3];   // [H,H]
    const float* bh = (const float*)d_in[4];   // [H]
    const float* Wo = (const float*)d_in[5];   // [O,H]
    const float* bo = (const float*)d_in[6];   // [O]
    float* out = (float*)d_out;                // [B,T,O] fp32

    const int M = BB * TT;                     // 131072 flattened rows

    // workspace layout: xproj fp32 [M,H] (134MB) | hs bf16 [M,H] (67MB)
    float* xproj = (float*)d_ws;
    unsigned short* hs = (unsigned short*)((char*)d_ws + (size_t)M * HH * sizeof(float));

    // Phase 1: xproj = x * Wi^T + bi
    gemm_f32_bt<<<dim3(M / BM, HH / BN), 256, 0, stream>>>(x, Wi, bi, xproj, M, HH, II);

    // Phase 2: sequential recurrence over T, batch-tiled via MFMA
    rnn_recurrence_mfma<<<dim3(4), 512, 0, stream>>>(xproj, Wh, bh, hs);

    // Phase 3: out = hs * Wo^T + bo  (hs columns are within-32 permuted;
    // gemm_bf16a_bt's As staging un-permutes)
    gemm_bf16a_bt<<<dim3(M / BM, OO / BN), 256, 0, stream>>>(
        hs, Wo, bo, out, M, OO, HH);
}